// Round 6
// baseline (392.172 us; speedup 1.0000x reference)
//
#include <hip/hip_runtime.h>
#include <hip/hip_bf16.h>

// out[n] = exp(-0.5 * 0.54 * ((x[n,0]-mu0)^2 + (x[n,1]-mu1)^2))
// Memory-bound: 12 B/point traffic. Vectorized: each iteration handles 4
// points = 2x float4 loads (32 B) + 1x float4 store (16 B).

__global__ __launch_bounds__(256) void gauss_pdf_kernel(
    const float4* __restrict__ x,   // N/2 float4 (each = 2 points)
    const float*  __restrict__ mu,  // 2 floats
    float4*       __restrict__ out, // N/4 float4
    int n4)                          // N/4
{
    const float mu0 = mu[0];
    const float mu1 = mu[1];

    int idx    = blockIdx.x * blockDim.x + threadIdx.x;
    int stride = gridDim.x * blockDim.x;

    for (int i = idx; i < n4; i += stride) {
        float4 a = x[2 * i];      // points 4i, 4i+1
        float4 b = x[2 * i + 1];  // points 4i+2, 4i+3

        float d0x = a.x - mu0, d0y = a.y - mu1;
        float d1x = a.z - mu0, d1y = a.w - mu1;
        float d2x = b.x - mu0, d2y = b.y - mu1;
        float d3x = b.z - mu0, d3y = b.w - mu1;

        float4 r;
        r.x = __expf(-0.27f * (d0x * d0x + d0y * d0y));
        r.y = __expf(-0.27f * (d1x * d1x + d1y * d1y));
        r.z = __expf(-0.27f * (d2x * d2x + d2y * d2y));
        r.w = __expf(-0.27f * (d3x * d3x + d3y * d3y));
        out[i] = r;
    }
}

extern "C" void kernel_launch(void* const* d_in, const int* in_sizes, int n_in,
                              void* d_out, int out_size, void* d_ws, size_t ws_size,
                              hipStream_t stream) {
    const float* x  = (const float*)d_in[0];  // [N,2] fp32
    const float* mu = (const float*)d_in[1];  // [2]   fp32
    float* out      = (float*)d_out;          // [N]   fp32

    const int n  = out_size;       // N = 2^25 (divisible by 4)
    const int n4 = n / 4;

    const int block = 256;
    int grid = 2048;               // grid-stride; ~8 blocks/CU across 256 CUs
    if (grid > (n4 + block - 1) / block) grid = (n4 + block - 1) / block;

    gauss_pdf_kernel<<<grid, block, 0, stream>>>(
        (const float4*)x, mu, (float4*)out, n4);
}

// Round 7
// 383.587 us; speedup vs baseline: 1.0224x; 1.0224x over previous
//
#include <hip/hip_runtime.h>
#include <hip/hip_bf16.h>

// out[n] = exp(-0.27 * ((x[n,0]-mu0)^2 + (x[n,1]-mu1)^2))
// Perfectly-coalesced variant: each lane loads one float4 (2 points,
// lane-contiguous 16 B) and stores one float2 (8 B, lane-contiguous).

__global__ __launch_bounds__(256) void gauss_pdf_kernel(
    const float4* __restrict__ x,   // N/2 float4 (each = 2 points)
    const float*  __restrict__ mu,  // 2 floats
    float2*       __restrict__ out, // N/2 float2
    int n2)                          // N/2
{
    const float mu0 = mu[0];
    const float mu1 = mu[1];

    int idx    = blockIdx.x * blockDim.x + threadIdx.x;
    int stride = gridDim.x * blockDim.x;

    for (int i = idx; i < n2; i += stride) {
        float4 a = x[i];            // points 2i, 2i+1

        float d0x = a.x - mu0, d0y = a.y - mu1;
        float d1x = a.z - mu0, d1y = a.w - mu1;

        float2 r;
        r.x = __expf(-0.27f * (d0x * d0x + d0y * d0y));
        r.y = __expf(-0.27f * (d1x * d1x + d1y * d1y));
        out[i] = r;
    }
}

extern "C" void kernel_launch(void* const* d_in, const int* in_sizes, int n_in,
                              void* d_out, int out_size, void* d_ws, size_t ws_size,
                              hipStream_t stream) {
    const float* x  = (const float*)d_in[0];  // [N,2] fp32
    const float* mu = (const float*)d_in[1];  // [2]   fp32
    float* out      = (float*)d_out;          // [N]   fp32

    const int n  = out_size;       // N = 2^25 (divisible by 2)
    const int n2 = n / 2;

    const int block = 256;
    int grid = 2048;               // grid-stride; 8 blocks/CU across 256 CUs
    if (grid > (n2 + block - 1) / block) grid = (n2 + block - 1) / block;

    gauss_pdf_kernel<<<grid, block, 0, stream>>>(
        (const float4*)x, mu, (float2*)out, n2);
}